// Round 15
// baseline (161.961 us; speedup 1.0000x reference)
//
#include <hip/hip_runtime.h>
#include <stdint.h>

typedef unsigned short u16;
typedef unsigned int u32;
typedef __attribute__((ext_vector_type(8))) __bf16 bf16x8;
typedef __attribute__((ext_vector_type(2))) __bf16 bf16x2;
typedef __attribute__((ext_vector_type(4))) float f32x4;
typedef __attribute__((ext_vector_type(16))) float f32x16;
typedef __attribute__((ext_vector_type(8))) u16 u16x8;
typedef __attribute__((ext_vector_type(4))) u32 u32x4;

#define Q_SCALE 0.1803368801111204f  /* 0.125 / ln(2): QK^T lands in log2 domain */

__device__ __forceinline__ float ex2(float x) { return __builtin_amdgcn_exp2f(x); }

__device__ __forceinline__ u16 f2bf(float f) {
  __bf16 h = (__bf16)f;
  return __builtin_bit_cast(u16, h);
}
__device__ __forceinline__ float bf2f(u16 u) {
  u32 x = ((u32)u) << 16;
  return __builtin_bit_cast(float, x);
}
__device__ __forceinline__ u32 pack2(float a, float b) {
  bf16x2 v; v.x = (__bf16)a; v.y = (__bf16)b;
  return __builtin_bit_cast(u32, v);
}
__device__ __forceinline__ void gl_lds16(const void* g, void* l) {
  __builtin_amdgcn_global_load_lds((const __attribute__((address_space(1))) void*)g,
                                   (__attribute__((address_space(3))) void*)l, 16, 0, 0);
}

// ------- 2. weight transpose W[k][n] -> WT[n][k] bf16 (cvt fused into GEMM)
__global__ __launch_bounds__(256) void prep_kernel(const float* __restrict__ Wq,
                                                   const float* __restrict__ Wk,
                                                   const float* __restrict__ Wv,
                                                   const float* __restrict__ Wo,
                                                   u16* __restrict__ wcatT,
                                                   u16* __restrict__ woT) {
  __shared__ u16 tile[64][72];
  int z = blockIdx.z;
  int t = threadIdx.x;
  const float* W = z == 0 ? Wq : z == 1 ? Wk : z == 2 ? Wv : Wo;
  int k0 = blockIdx.y * 64, n0 = blockIdx.x * 64;
  int r = t >> 2, c0 = (t & 3) * 16;
  const float* src = W + (size_t)(k0 + r) * 1024 + n0 + c0;
#pragma unroll
  for (int i = 0; i < 16; i += 4) {
    float4 x = *(const float4*)(src + i);
    tile[r][c0 + i] = f2bf(x.x); tile[r][c0 + i + 1] = f2bf(x.y);
    tile[r][c0 + i + 2] = f2bf(x.z); tile[r][c0 + i + 3] = f2bf(x.w);
  }
  __syncthreads();
  int n = t >> 2, kc = (t & 3) * 16;
  u16x8 o0, o1;
#pragma unroll
  for (int j = 0; j < 8; ++j) { o0[j] = tile[kc + j][n]; o1[j] = tile[kc + 8 + j][n]; }
  u16* dst = (z < 3) ? (wcatT + (size_t)z * 1048576 + (size_t)(n0 + n) * 1024 + k0 + kc)
                     : (woT + (size_t)(n0 + n) * 1024 + k0 + kc);
  *(u16x8*)dst = o0;
  *(u16x8*)(dst + 8) = o1;
}

// ---------------- 3. GEMM mode0: QKV proj, 128x128 tile, BK=32, 8 waves -----
__global__ __launch_bounds__(512) void gemm_bt(const float* __restrict__ Aq,
                                               const float* __restrict__ Ak,
                                               const float* __restrict__ Av,
                                               const u16* __restrict__ BT,
                                               u16* __restrict__ outBF,
                                               const float* __restrict__ b0,
                                               const float* __restrict__ b1,
                                               const float* __restrict__ b2) {
  __shared__ u16 As[2][4096];
  __shared__ u16 Bs[2][4096];
  int tid = threadIdx.x;
  int bid = blockIdx.y * 8 + blockIdx.x;
  int cpx = gridDim.y;
  int swz = (bid & 7) * cpx + (bid >> 3);
  int m0 = (swz >> 3) * 128, n0 = (swz & 7) * 128;
  int sec = m0 >> 12;                     // block-uniform section
  const float* A32 = sec == 0 ? Aq : sec == 1 ? Ak : Av;
  int mbase = m0 & 4095;
  const u16* bt = BT + (size_t)sec * 1048576;
  int w = tid >> 6, l = tid & 63;
  int wr = w >> 1, wc = w & 1;            // wave tile 32x64
  f32x4 acc[2][4];
#pragma unroll
  for (int i = 0; i < 2; ++i)
#pragma unroll
    for (int j = 0; j < 4; ++j)
#pragma unroll
      for (int rr = 0; rr < 4; ++rr) acc[i][j][rr] = 0.f;

  int rS = tid >> 2, cpS = tid & 3;
  int clS = cpS ^ ((rS ^ (rS >> 2)) & 3);
  const float* srcA = A32 + (size_t)(mbase + rS) * 1024 + clS * 8;
  const u16* srcB = bt + (size_t)(n0 + rS) * 1024 + clS * 8;
  int dstS = tid * 8;
  float4 pa, pb4;
  auto loadA = [&](int kt) {
    pa = *(const float4*)(srcA + kt * 32);
    pb4 = *(const float4*)(srcA + kt * 32 + 4);
  };
  auto writeA = [&](int buf) {
    u16x8 o;
    o[0] = f2bf(pa.x); o[1] = f2bf(pa.y); o[2] = f2bf(pa.z); o[3] = f2bf(pa.w);
    o[4] = f2bf(pb4.x); o[5] = f2bf(pb4.y); o[6] = f2bf(pb4.z); o[7] = f2bf(pb4.w);
    *(u16x8*)&As[buf][dstS] = o;
  };
  auto stageB = [&](int buf, int kt) {
    gl_lds16(srcB + kt * 32, &Bs[buf][dstS]);
  };
  loadA(0);
  stageB(0, 0);
  writeA(0);
  __syncthreads();
  int sw = (l & 3) ^ ((l >> 2) & 3);
  int phys = (l >> 4) ^ sw;
  for (int kt = 0; kt < 32; ++kt) {
    int buf = kt & 1;
    if (kt < 31) {
      loadA(kt + 1);
      stageB(buf ^ 1, kt + 1);
    }
    bf16x8 af[2], bfr[4];
#pragma unroll
    for (int mi = 0; mi < 2; ++mi) {
      int row = wr * 32 + mi * 16 + (l & 15);
      af[mi] = *(const bf16x8*)&As[buf][row * 32 + phys * 8];
    }
#pragma unroll
    for (int nj = 0; nj < 4; ++nj) {
      int rowb = wc * 64 + nj * 16 + (l & 15);
      bfr[nj] = *(const bf16x8*)&Bs[buf][rowb * 32 + phys * 8];
    }
#pragma unroll
    for (int mi = 0; mi < 2; ++mi)
#pragma unroll
      for (int nj = 0; nj < 4; ++nj)
        acc[mi][nj] = __builtin_amdgcn_mfma_f32_16x16x32_bf16(af[mi], bfr[nj],
                                                              acc[mi][nj], 0, 0, 0);
    if (kt < 31) writeA(buf ^ 1);
    __syncthreads();
  }
  const float* bp = sec == 0 ? b0 : sec == 1 ? b1 : b2;
#pragma unroll
  for (int mi = 0; mi < 2; ++mi)
#pragma unroll
    for (int nj = 0; nj < 4; ++nj)
#pragma unroll
      for (int rr = 0; rr < 4; ++rr) {
        int orow = mbase + wr * 32 + mi * 16 + (l >> 4) * 4 + rr;
        int col = n0 + wc * 64 + nj * 16 + (l & 15);
        float vv = acc[mi][nj][rr] + bp[col];
        if (sec == 0) vv *= Q_SCALE;   // fold 1/(8*ln2) into Q (exp2 softmax)
        outBF[(size_t)sec * 4194304 + (size_t)orow * 1024 + col] = f2bf(vv);
      }
}

// ---------------- 6. GEMM mode1: O-proj, 128x64 tile, 8 waves ---------------
__global__ __launch_bounds__(512) void gemm_n64(const u16* __restrict__ A,
                                                const u16* __restrict__ BT,
                                                float* __restrict__ outF,
                                                const float* __restrict__ b0,
                                                const float* __restrict__ resid) {
  __shared__ u16 As[2][4096];
  __shared__ u16 Bs[2][2048];
  int tid = threadIdx.x;
  int bid = blockIdx.y * 8 + blockIdx.x;   // grid (8,64) = 512
  int swz = (bid & 7) * 64 + (bid >> 3);   // XCD chunk of 64
  int m0 = (swz >> 4) * 128, n0 = (swz & 15) * 64;
  int w = tid >> 6, l = tid & 63;
  int wr = w >> 1, wc = w & 1;             // wave tile 32x32
  f32x4 acc[2][2];
#pragma unroll
  for (int i = 0; i < 2; ++i)
#pragma unroll
    for (int j = 0; j < 2; ++j)
#pragma unroll
      for (int rr = 0; rr < 4; ++rr) acc[i][j][rr] = 0.f;

  int rS = tid >> 2, cpS = tid & 3;
  int clS = cpS ^ ((rS ^ (rS >> 2)) & 3);
  const u16* srcA = A + (size_t)(m0 + rS) * 1024 + clS * 8;
  const u16* srcB = BT + (size_t)(n0 + rS) * 1024 + clS * 8;  // rS<64 only
  int dstS = tid * 8;
  auto stage = [&](int buf, int kt) {
    gl_lds16(srcA + kt * 32, &As[buf][dstS]);
    if (tid < 256) gl_lds16(srcB + kt * 32, &Bs[buf][dstS]);
  };
  stage(0, 0);
  __syncthreads();
  int sw = (l & 3) ^ ((l >> 2) & 3);
  int phys = (l >> 4) ^ sw;
  for (int kt = 0; kt < 32; ++kt) {
    int buf = kt & 1;
    if (kt < 31) stage(buf ^ 1, kt + 1);
    bf16x8 af[2], bfr[2];
#pragma unroll
    for (int mi = 0; mi < 2; ++mi) {
      int row = wr * 32 + mi * 16 + (l & 15);
      af[mi] = *(const bf16x8*)&As[buf][row * 32 + phys * 8];
    }
#pragma unroll
    for (int nj = 0; nj < 2; ++nj) {
      int rowb = wc * 32 + nj * 16 + (l & 15);
      bfr[nj] = *(const bf16x8*)&Bs[buf][rowb * 32 + phys * 8];
    }
#pragma unroll
    for (int mi = 0; mi < 2; ++mi)
#pragma unroll
      for (int nj = 0; nj < 2; ++nj)
        acc[mi][nj] = __builtin_amdgcn_mfma_f32_16x16x32_bf16(af[mi], bfr[nj],
                                                              acc[mi][nj], 0, 0, 0);
    __syncthreads();
  }
#pragma unroll
  for (int mi = 0; mi < 2; ++mi)
#pragma unroll
    for (int nj = 0; nj < 2; ++nj)
#pragma unroll
      for (int rr = 0; rr < 4; ++rr) {
        int row = m0 + wr * 32 + mi * 16 + (l >> 4) * 4 + rr;
        int col = n0 + wc * 32 + nj * 16 + (l & 15);
        outF[(size_t)row * 1024 + col] =
            acc[mi][nj][rr] + b0[col] + resid[(size_t)row * 1024 + col];
      }
}

// ---------------- 4. V transpose per head: vp[n][h*64+d] -> vt[h][d][n] ----
__global__ __launch_bounds__(256) void vtrans_kernel(const u16* __restrict__ vp,
                                                     u16* __restrict__ vt) {
  __shared__ u16 tile[64][72];
  int t = threadIdx.x;
  int n0 = blockIdx.x * 64, h = blockIdx.y;
  int r = t >> 2, c0 = (t & 3) * 16;
  u16x8 a = *(const u16x8*)(vp + (size_t)(n0 + r) * 1024 + h * 64 + c0);
  u16x8 b = *(const u16x8*)(vp + (size_t)(n0 + r) * 1024 + h * 64 + c0 + 8);
#pragma unroll
  for (int j = 0; j < 8; ++j) { tile[r][c0 + j] = a[j]; tile[r][c0 + 8 + j] = b[j]; }
  __syncthreads();
  int d = t >> 2, nc = (t & 3) * 16;
  u16x8 o0, o1;
#pragma unroll
  for (int j = 0; j < 8; ++j) { o0[j] = tile[nc + j][d]; o1[j] = tile[nc + 8 + j][d]; }
  size_t base = (size_t)(h * 64 + d) * 4096 + n0 + nc;
  *(u16x8*)(vt + base) = o0;
  *(u16x8*)(vt + base + 8) = o1;
}

// ---------------- 5. flash attention + T15 cross-tile pipeline --------------
// R7 structure, but PV deferred one tile: iteration t computes QK(t) and
// PV(t-1) (pb fragments kept in registers), so PV's MFMAs are independent of
// this tile's softmax and the serial chain shrinks to QK->SM. K and V have
// separate double-buffers; V(t) is staged during iter t (one tile late) so
// PV(t-1)'s buffer is never being overwritten. Barrier count unchanged.
__global__ __launch_bounds__(512, 4) void attn_kernel(const u16* __restrict__ qp,
                                                      const u16* __restrict__ kp,
                                                      const u16* __restrict__ vt,
                                                      u16* __restrict__ attout) {
  __shared__ u16 smem[32768];  // 64KB/half=32KB: [K dbuf 8|8KB][V dbuf 8|8KB]
  int tid = threadIdx.x;
  int w = tid >> 6, l = tid & 63;
  int half = w >> 2, wl = w & 3;
  int hi = l >> 5, l31 = l & 31;
  int h = blockIdx.y, bx = blockIdx.x;
  int qrow = bx * 128 + wl * 32 + l31;
  bf16x8 qf[4];
#pragma unroll
  for (int ds = 0; ds < 4; ++ds)
    qf[ds] = *(const bf16x8*)(qp + (size_t)qrow * 1024 + h * 64 + ds * 16 + hi * 8);

  f32x16 zero16;
#pragma unroll
  for (int r = 0; r < 16; ++r) zero16[r] = 0.f;
  f32x16 accO[2];
#pragma unroll
  for (int r = 0; r < 16; ++r) { accO[0][r] = 0.f; accO[1][r] = 0.f; }
  float l_run = 0.f;

  u16* sbase = smem + half * 16384;
  int ht = (wl << 6) | l;  // half-local thread id, 0..255
  const u16* srcK[2]; const u16* srcV[2]; int dstOff[2];
#pragma unroll
  for (int i = 0; i < 2; ++i) {
    int id = i * 256 + ht;
    int r = id >> 3, cp = id & 7;
    int cl = cp ^ ((r ^ (r >> 3)) & 7);  // inverse swizzle on source (rule #21)
    srcK[i] = kp + (size_t)(half * 2048 + r) * 1024 + h * 64 + cl * 8;
    srcV[i] = vt + (size_t)(h * 64 + r) * 4096 + half * 2048 + cl * 8;
    dstOff[i] = id * 8;
  }
  auto stageK = [&](int buf, int kt) {
    u16* b = sbase + buf * 4096;
#pragma unroll
    for (int i = 0; i < 2; ++i)
      gl_lds16(srcK[i] + (size_t)kt * 65536, b + dstOff[i]);
  };
  auto stageV = [&](int buf, int kt) {
    u16* b = sbase + 8192 + buf * 4096;
#pragma unroll
    for (int i = 0; i < 2; ++i)
      gl_lds16(srcV[i] + kt * 64, b + dstOff[i]);
  };
  stageK(0, 0);
  __syncthreads();

  bf16x8 pb[4];   // P^T fragments of PREVIOUS tile (persist across barrier)
  for (int kt = 0; kt < 32; ++kt) {
    int kb = kt & 1;
    if (kt < 31) stageK(kb ^ 1, kt + 1);
    stageV(kb, kt);                     // V(kt), consumed by PV at iter kt+1
    const u16* Kt = sbase + kb * 4096;

    // QK(kt): S^T = K @ Q^T (rows kv, cols q), log2 domain (Q pre-scaled)
    f32x16 accS[2];
    __builtin_amdgcn_s_setprio(1);
#pragma unroll
    for (int mt = 0; mt < 2; ++mt) {
      int row = mt * 32 + l31;
      int g = (row ^ (row >> 3)) & 7;
      {
        bf16x8 kf = *(const bf16x8*)(Kt + row * 64 + ((0 + hi) ^ g) * 8);
        accS[mt] = __builtin_amdgcn_mfma_f32_32x32x16_bf16(kf, qf[0], zero16, 0, 0, 0);
      }
#pragma unroll
      for (int ds = 1; ds < 4; ++ds) {
        int phys = (2 * ds + hi) ^ g;
        bf16x8 kf = *(const bf16x8*)(Kt + row * 64 + phys * 8);
        accS[mt] = __builtin_amdgcn_mfma_f32_32x32x16_bf16(kf, qf[ds], accS[mt], 0, 0, 0);
      }
    }
    // PV(kt-1): independent of QK(kt)/SM(kt) — fills the MFMA pipe while
    // softmax VALU runs. Reads vbuf[(kt-1)&1], not the buffer being staged.
    if (kt > 0) {
      const u16* Vt = sbase + 8192 + ((kt - 1) & 1) * 4096;
#pragma unroll
      for (int mto = 0; mto < 2; ++mto) {
        int row = mto * 32 + l31;
        int g = (row ^ (row >> 3)) & 7;
#pragma unroll
        for (int ks = 0; ks < 4; ++ks) {
          int phys = (2 * ks + hi) ^ g;
          bf16x8 vf = *(const bf16x8*)(Vt + row * 64 + phys * 8);
          accO[mto] = __builtin_amdgcn_mfma_f32_32x32x16_bf16(vf, pb[ks], accO[mto], 0, 0, 0);
        }
      }
    }
    __builtin_amdgcn_s_setprio(0);

    // SM(kt): p = exp2(s); l partials on VALU (cross-lane shfl deferred);
    // pb overwritten AFTER PV(kt-1) consumed the old fragments.
    u32 pku[2][8];
    float s0 = 0.f, s1 = 0.f, s2 = 0.f, s3 = 0.f;
#pragma unroll
    for (int mt = 0; mt < 2; ++mt)
#pragma unroll
      for (int qd = 0; qd < 8; ++qd) {
        float a = ex2(accS[mt][2 * qd]);
        float b = ex2(accS[mt][2 * qd + 1]);
        if (qd & 1) { s2 += a; s3 += b; } else { s0 += a; s1 += b; }
        pku[mt][qd] = pack2(a, b);
      }
    l_run += (s0 + s1) + (s2 + s3);
#pragma unroll
    for (int ks = 0; ks < 4; ++ks) {
      const int mt = ks >> 1, k1 = ks & 1;
      u32 a0 = pku[mt][4 * k1 + 0], c0 = pku[mt][4 * k1 + 2];
      u32 a1 = pku[mt][4 * k1 + 1], c1 = pku[mt][4 * k1 + 3];
      asm("v_permlane32_swap_b32 %0, %1" : "+v"(a0), "+v"(c0));
      asm("v_permlane32_swap_b32 %0, %1" : "+v"(a1), "+v"(c1));
      u32x4 fr;
      fr[0] = a0; fr[1] = a1; fr[2] = c0; fr[3] = c1;
      pb[ks] = __builtin_bit_cast(bf16x8, fr);
    }
    __syncthreads();
  }
  // epilogue PV(31)
  {
    const u16* Vt = sbase + 8192 + (31 & 1) * 4096;
    __builtin_amdgcn_s_setprio(1);
#pragma unroll
    for (int mto = 0; mto < 2; ++mto) {
      int row = mto * 32 + l31;
      int g = (row ^ (row >> 3)) & 7;
#pragma unroll
      for (int ks = 0; ks < 4; ++ks) {
        int phys = (2 * ks + hi) ^ g;
        bf16x8 vf = *(const bf16x8*)(Vt + row * 64 + phys * 8);
        accO[mto] = __builtin_amdgcn_mfma_f32_32x32x16_bf16(vf, pb[ks], accO[mto], 0, 0, 0);
      }
    }
    __builtin_amdgcn_s_setprio(0);
  }
  l_run += __shfl_xor(l_run, 32, 64);   // deferred cross-lane l reduce
  __syncthreads();                      // all PV reads done before smem reuse

  // -------- cross-half combine: O = (O_A + O_B) / (l_A + l_B) --------
  u16* pO = smem;
  float* ml = (float*)(smem + 2 * 128 * 72);
  int q = wl * 32 + l31;
#pragma unroll
  for (int mto = 0; mto < 2; ++mto)
#pragma unroll
    for (int g = 0; g < 4; ++g)
#pragma unroll
      for (int j = 0; j < 2; ++j) {
        int r = g * 4 + j * 2;
        int d = j * 2 + 8 * g + 4 * hi + 32 * mto;
        u32 pk = pack2(accO[mto][r], accO[mto][r + 1]);
        *(u32*)&pO[(size_t)(half * 128 + q) * 72 + d] = pk;
      }
  if (hi == 0) ml[half * 128 + q] = l_run;
  __syncthreads();
  {
    int qq = tid >> 2, d0 = (tid & 3) * 16;   // 512 thr x 16 cols = 128x64
    float invL = 1.f / (ml[qq] + ml[128 + qq]);
    u16x8 ra0 = *(u16x8*)&pO[(size_t)qq * 72 + d0];
    u16x8 ra1 = *(u16x8*)&pO[(size_t)qq * 72 + d0 + 8];
    u16x8 rb0 = *(u16x8*)&pO[(size_t)(128 + qq) * 72 + d0];
    u16x8 rb1 = *(u16x8*)&pO[(size_t)(128 + qq) * 72 + d0 + 8];
    u16x8 o0, o1;
#pragma unroll
    for (int j = 0; j < 8; ++j) {
      o0[j] = f2bf((bf2f(ra0[j]) + bf2f(rb0[j])) * invL);
      o1[j] = f2bf((bf2f(ra1[j]) + bf2f(rb1[j])) * invL);
    }
    size_t ob = (size_t)(bx * 128 + qq) * 1024 + (size_t)h * 64 + d0;
    *(u16x8*)(attout + ob) = o0;
    *(u16x8*)(attout + ob + 8) = o1;
  }
}

// ---------------- 7. LayerNorm in-place on d_out ----------------------------
__global__ __launch_bounds__(256) void ln_kernel(float* __restrict__ io,
                                                 const float* __restrict__ gamma,
                                                 const float* __restrict__ beta) {
  int row = blockIdx.x, t = threadIdx.x;
  float4 v = *(const float4*)(io + (size_t)row * 1024 + t * 4);
  float s = v.x + v.y + v.z + v.w;
  float sq = v.x * v.x + v.y * v.y + v.z * v.z + v.w * v.w;
#pragma unroll
  for (int off = 1; off < 64; off <<= 1) {
    s += __shfl_xor(s, off, 64);
    sq += __shfl_xor(sq, off, 64);
  }
  __shared__ float rs[4], rq[4];
  if ((t & 63) == 0) { rs[t >> 6] = s; rq[t >> 6] = sq; }
  __syncthreads();
  float S = rs[0] + rs[1] + rs[2] + rs[3];
  float Q = rq[0] + rq[1] + rq[2] + rq[3];
  float mu = S * (1.f / 1024.f);
  float var = Q * (1.f / 1024.f) - mu * mu;
  float invs = rsqrtf(var + 1e-12f);
  float4 g = *(const float4*)(gamma + t * 4);
  float4 b = *(const float4*)(beta + t * 4);
  float4 o;
  o.x = (v.x - mu) * invs * g.x + b.x;
  o.y = (v.y - mu) * invs * g.y + b.y;
  o.z = (v.z - mu) * invs * g.z + b.z;
  o.w = (v.w - mu) * invs * g.w + b.w;
  *(float4*)(io + (size_t)row * 1024 + t * 4) = o;
}

extern "C" void kernel_launch(void* const* d_in, const int* in_sizes, int n_in,
                              void* d_out, int out_size, void* d_ws, size_t ws_size,
                              hipStream_t stream) {
  (void)in_sizes; (void)n_in; (void)out_size; (void)ws_size;
  const float* queries = (const float*)d_in[0];
  const float* keys    = (const float*)d_in[1];
  const float* values  = (const float*)d_in[2];
  const float* Wq = (const float*)d_in[3];
  const float* bq = (const float*)d_in[4];
  const float* Wk = (const float*)d_in[5];
  const float* bk = (const float*)d_in[6];
  const float* Wv = (const float*)d_in[7];
  const float* bv = (const float*)d_in[8];
  const float* Wo = (const float*)d_in[9];
  const float* bo = (const float*)d_in[10];
  const float* gamma = (const float*)d_in[11];
  const float* beta  = (const float*)d_in[12];
  float* out = (float*)d_out;

  u16* ws = (u16*)d_ws;
  u16* attout = ws;                 // 4096x1024
  u16* vt     = ws + 4194304;       // [16][64][4096]
  u16* wcatT  = ws + 12582912;      // 3x 1024x1024
  u16* woT    = ws + 15728640;      // 1024x1024
  u16* qp     = ws + 16777216;      // q,k,v projections contiguous
  u16* kp     = qp + 4194304;
  u16* vp     = qp + 8388608;

  prep_kernel<<<dim3(16, 16, 4), dim3(256), 0, stream>>>(Wq, Wk, Wv, Wo, wcatT, woT);
  gemm_bt<<<dim3(8, 96), dim3(512), 0, stream>>>(queries, keys, values, wcatT, qp,
                                                 bq, bk, bv);
  vtrans_kernel<<<dim3(64, 16), dim3(256), 0, stream>>>(vp, vt);
  attn_kernel<<<dim3(32, 16), dim3(512), 0, stream>>>(qp, kp, vt, attout);
  gemm_n64<<<dim3(8, 64), dim3(512), 0, stream>>>(attout, woT, out, bo, queries);
  ln_kernel<<<dim3(4096), dim3(256), 0, stream>>>(out, gamma, beta);
}

// Round 16
// 160.442 us; speedup vs baseline: 1.0095x; 1.0095x over previous
//
#include <hip/hip_runtime.h>
#include <stdint.h>

typedef unsigned short u16;
typedef unsigned int u32;
typedef __attribute__((ext_vector_type(8))) __bf16 bf16x8;
typedef __attribute__((ext_vector_type(2))) __bf16 bf16x2;
typedef __attribute__((ext_vector_type(4))) float f32x4;
typedef __attribute__((ext_vector_type(16))) float f32x16;
typedef __attribute__((ext_vector_type(8))) u16 u16x8;
typedef __attribute__((ext_vector_type(4))) u32 u32x4;

#define Q_SCALE 0.1803368801111204f  /* 0.125 / ln(2): QK^T lands in log2 domain */

__device__ __forceinline__ float ex2(float x) { return __builtin_amdgcn_exp2f(x); }

__device__ __forceinline__ u16 f2bf(float f) {
  __bf16 h = (__bf16)f;
  return __builtin_bit_cast(u16, h);
}
__device__ __forceinline__ float bf2f(u16 u) {
  u32 x = ((u32)u) << 16;
  return __builtin_bit_cast(float, x);
}
__device__ __forceinline__ u32 pack2(float a, float b) {
  bf16x2 v; v.x = (__bf16)a; v.y = (__bf16)b;
  return __builtin_bit_cast(u32, v);
}
__device__ __forceinline__ void gl_lds16(const void* g, void* l) {
  __builtin_amdgcn_global_load_lds((const __attribute__((address_space(1))) void*)g,
                                   (__attribute__((address_space(3))) void*)l, 16, 0, 0);
}

// ------- 2. weight transpose W[k][n] -> WT[n][k] bf16 (cvt fused into GEMM)
__global__ __launch_bounds__(256) void prep_kernel(const float* __restrict__ Wq,
                                                   const float* __restrict__ Wk,
                                                   const float* __restrict__ Wv,
                                                   const float* __restrict__ Wo,
                                                   u16* __restrict__ wcatT,
                                                   u16* __restrict__ woT) {
  __shared__ u16 tile[64][72];
  int z = blockIdx.z;
  int t = threadIdx.x;
  const float* W = z == 0 ? Wq : z == 1 ? Wk : z == 2 ? Wv : Wo;
  int k0 = blockIdx.y * 64, n0 = blockIdx.x * 64;
  int r = t >> 2, c0 = (t & 3) * 16;
  const float* src = W + (size_t)(k0 + r) * 1024 + n0 + c0;
#pragma unroll
  for (int i = 0; i < 16; i += 4) {
    float4 x = *(const float4*)(src + i);
    tile[r][c0 + i] = f2bf(x.x); tile[r][c0 + i + 1] = f2bf(x.y);
    tile[r][c0 + i + 2] = f2bf(x.z); tile[r][c0 + i + 3] = f2bf(x.w);
  }
  __syncthreads();
  int n = t >> 2, kc = (t & 3) * 16;
  u16x8 o0, o1;
#pragma unroll
  for (int j = 0; j < 8; ++j) { o0[j] = tile[kc + j][n]; o1[j] = tile[kc + 8 + j][n]; }
  u16* dst = (z < 3) ? (wcatT + (size_t)z * 1048576 + (size_t)(n0 + n) * 1024 + k0 + kc)
                     : (woT + (size_t)(n0 + n) * 1024 + k0 + kc);
  *(u16x8*)dst = o0;
  *(u16x8*)(dst + 8) = o1;
}

// ---------------- 3. GEMM mode0: QKV proj, 128x128 tile, BK=32, 8 waves -----
__global__ __launch_bounds__(512) void gemm_bt(const float* __restrict__ Aq,
                                               const float* __restrict__ Ak,
                                               const float* __restrict__ Av,
                                               const u16* __restrict__ BT,
                                               u16* __restrict__ outBF,
                                               const float* __restrict__ b0,
                                               const float* __restrict__ b1,
                                               const float* __restrict__ b2) {
  __shared__ u16 As[2][4096];
  __shared__ u16 Bs[2][4096];
  int tid = threadIdx.x;
  int bid = blockIdx.y * 8 + blockIdx.x;
  int cpx = gridDim.y;
  int swz = (bid & 7) * cpx + (bid >> 3);
  int m0 = (swz >> 3) * 128, n0 = (swz & 7) * 128;
  int sec = m0 >> 12;                     // block-uniform section
  const float* A32 = sec == 0 ? Aq : sec == 1 ? Ak : Av;
  int mbase = m0 & 4095;
  const u16* bt = BT + (size_t)sec * 1048576;
  int w = tid >> 6, l = tid & 63;
  int wr = w >> 1, wc = w & 1;            // wave tile 32x64
  f32x4 acc[2][4];
#pragma unroll
  for (int i = 0; i < 2; ++i)
#pragma unroll
    for (int j = 0; j < 4; ++j)
#pragma unroll
      for (int rr = 0; rr < 4; ++rr) acc[i][j][rr] = 0.f;

  int rS = tid >> 2, cpS = tid & 3;
  int clS = cpS ^ ((rS ^ (rS >> 2)) & 3);
  const float* srcA = A32 + (size_t)(mbase + rS) * 1024 + clS * 8;
  const u16* srcB = bt + (size_t)(n0 + rS) * 1024 + clS * 8;
  int dstS = tid * 8;
  float4 pa, pb4;
  auto loadA = [&](int kt) {
    pa = *(const float4*)(srcA + kt * 32);
    pb4 = *(const float4*)(srcA + kt * 32 + 4);
  };
  auto writeA = [&](int buf) {
    u16x8 o;
    o[0] = f2bf(pa.x); o[1] = f2bf(pa.y); o[2] = f2bf(pa.z); o[3] = f2bf(pa.w);
    o[4] = f2bf(pb4.x); o[5] = f2bf(pb4.y); o[6] = f2bf(pb4.z); o[7] = f2bf(pb4.w);
    *(u16x8*)&As[buf][dstS] = o;
  };
  auto stageB = [&](int buf, int kt) {
    gl_lds16(srcB + kt * 32, &Bs[buf][dstS]);
  };
  loadA(0);
  stageB(0, 0);
  writeA(0);
  __syncthreads();
  int sw = (l & 3) ^ ((l >> 2) & 3);
  int phys = (l >> 4) ^ sw;
  for (int kt = 0; kt < 32; ++kt) {
    int buf = kt & 1;
    if (kt < 31) {
      loadA(kt + 1);
      stageB(buf ^ 1, kt + 1);
    }
    bf16x8 af[2], bfr[4];
#pragma unroll
    for (int mi = 0; mi < 2; ++mi) {
      int row = wr * 32 + mi * 16 + (l & 15);
      af[mi] = *(const bf16x8*)&As[buf][row * 32 + phys * 8];
    }
#pragma unroll
    for (int nj = 0; nj < 4; ++nj) {
      int rowb = wc * 64 + nj * 16 + (l & 15);
      bfr[nj] = *(const bf16x8*)&Bs[buf][rowb * 32 + phys * 8];
    }
#pragma unroll
    for (int mi = 0; mi < 2; ++mi)
#pragma unroll
      for (int nj = 0; nj < 4; ++nj)
        acc[mi][nj] = __builtin_amdgcn_mfma_f32_16x16x32_bf16(af[mi], bfr[nj],
                                                              acc[mi][nj], 0, 0, 0);
    if (kt < 31) writeA(buf ^ 1);
    __syncthreads();
  }
  const float* bp = sec == 0 ? b0 : sec == 1 ? b1 : b2;
#pragma unroll
  for (int mi = 0; mi < 2; ++mi)
#pragma unroll
    for (int nj = 0; nj < 4; ++nj)
#pragma unroll
      for (int rr = 0; rr < 4; ++rr) {
        int orow = mbase + wr * 32 + mi * 16 + (l >> 4) * 4 + rr;
        int col = n0 + wc * 64 + nj * 16 + (l & 15);
        float vv = acc[mi][nj][rr] + bp[col];
        if (sec == 0) vv *= Q_SCALE;   // fold 1/(8*ln2) into Q (exp2 softmax)
        outBF[(size_t)sec * 4194304 + (size_t)orow * 1024 + col] = f2bf(vv);
      }
}

// ---------------- 6. GEMM mode1: O-proj, 128x64 tile, 8 waves ---------------
__global__ __launch_bounds__(512) void gemm_n64(const u16* __restrict__ A,
                                                const u16* __restrict__ BT,
                                                float* __restrict__ outF,
                                                const float* __restrict__ b0,
                                                const float* __restrict__ resid) {
  __shared__ u16 As[2][4096];
  __shared__ u16 Bs[2][2048];
  int tid = threadIdx.x;
  int bid = blockIdx.y * 8 + blockIdx.x;   // grid (8,64) = 512
  int swz = (bid & 7) * 64 + (bid >> 3);   // XCD chunk of 64
  int m0 = (swz >> 4) * 128, n0 = (swz & 15) * 64;
  int w = tid >> 6, l = tid & 63;
  int wr = w >> 1, wc = w & 1;             // wave tile 32x32
  f32x4 acc[2][2];
#pragma unroll
  for (int i = 0; i < 2; ++i)
#pragma unroll
    for (int j = 0; j < 2; ++j)
#pragma unroll
      for (int rr = 0; rr < 4; ++rr) acc[i][j][rr] = 0.f;

  int rS = tid >> 2, cpS = tid & 3;
  int clS = cpS ^ ((rS ^ (rS >> 2)) & 3);
  const u16* srcA = A + (size_t)(m0 + rS) * 1024 + clS * 8;
  const u16* srcB = BT + (size_t)(n0 + rS) * 1024 + clS * 8;  // rS<64 only
  int dstS = tid * 8;
  auto stage = [&](int buf, int kt) {
    gl_lds16(srcA + kt * 32, &As[buf][dstS]);
    if (tid < 256) gl_lds16(srcB + kt * 32, &Bs[buf][dstS]);
  };
  stage(0, 0);
  __syncthreads();
  int sw = (l & 3) ^ ((l >> 2) & 3);
  int phys = (l >> 4) ^ sw;
  for (int kt = 0; kt < 32; ++kt) {
    int buf = kt & 1;
    if (kt < 31) stage(buf ^ 1, kt + 1);
    bf16x8 af[2], bfr[2];
#pragma unroll
    for (int mi = 0; mi < 2; ++mi) {
      int row = wr * 32 + mi * 16 + (l & 15);
      af[mi] = *(const bf16x8*)&As[buf][row * 32 + phys * 8];
    }
#pragma unroll
    for (int nj = 0; nj < 2; ++nj) {
      int rowb = wc * 32 + nj * 16 + (l & 15);
      bfr[nj] = *(const bf16x8*)&Bs[buf][rowb * 32 + phys * 8];
    }
#pragma unroll
    for (int mi = 0; mi < 2; ++mi)
#pragma unroll
      for (int nj = 0; nj < 2; ++nj)
        acc[mi][nj] = __builtin_amdgcn_mfma_f32_16x16x32_bf16(af[mi], bfr[nj],
                                                              acc[mi][nj], 0, 0, 0);
    __syncthreads();
  }
#pragma unroll
  for (int mi = 0; mi < 2; ++mi)
#pragma unroll
    for (int nj = 0; nj < 2; ++nj)
#pragma unroll
      for (int rr = 0; rr < 4; ++rr) {
        int row = m0 + wr * 32 + mi * 16 + (l >> 4) * 4 + rr;
        int col = n0 + wc * 32 + nj * 16 + (l & 15);
        outF[(size_t)row * 1024 + col] =
            acc[mi][nj][rr] + b0[col] + resid[(size_t)row * 1024 + col];
      }
}

// ---------------- 4. V transpose per head: vp[n][h*64+d] -> vt[h][d][n] ----
__global__ __launch_bounds__(256) void vtrans_kernel(const u16* __restrict__ vp,
                                                     u16* __restrict__ vt) {
  __shared__ u16 tile[64][72];
  int t = threadIdx.x;
  int n0 = blockIdx.x * 64, h = blockIdx.y;
  int r = t >> 2, c0 = (t & 3) * 16;
  u16x8 a = *(const u16x8*)(vp + (size_t)(n0 + r) * 1024 + h * 64 + c0);
  u16x8 b = *(const u16x8*)(vp + (size_t)(n0 + r) * 1024 + h * 64 + c0 + 8);
#pragma unroll
  for (int j = 0; j < 8; ++j) { tile[r][c0 + j] = a[j]; tile[r][c0 + 8 + j] = b[j]; }
  __syncthreads();
  int d = t >> 2, nc = (t & 3) * 16;
  u16x8 o0, o1;
#pragma unroll
  for (int j = 0; j < 8; ++j) { o0[j] = tile[nc + j][d]; o1[j] = tile[nc + 8 + j][d]; }
  size_t base = (size_t)(h * 64 + d) * 4096 + n0 + nc;
  *(u16x8*)(vt + base) = o0;
  *(u16x8*)(vt + base + 8) = o1;
}

// ---------------- 5. flash attention, intra-block KV split (R7/R14 frozen) --
// 8 waves = 512 thr, 128 q rows; waves 0-3 stream KV[0,2048), waves 4-7
// KV[2048,4096), own dbuf LDS each. Max-free exp2 softmax; l-sum on VALU
// (cross-lane shfl deferred out of the loop); P^T B-frags via
// v_permlane32_swap_b32 (T12); conflict-free LDS swizzle g=(r^(r>>3))&7.
// Six restructures (interleave, occupancy x2, XCD locality, KVBLK=32, T15
// PV-deferral) all failed to beat this schedule - do not touch.
__global__ __launch_bounds__(512, 4) void attn_kernel(const u16* __restrict__ qp,
                                                      const u16* __restrict__ kp,
                                                      const u16* __restrict__ vt,
                                                      u16* __restrict__ attout) {
  __shared__ u16 smem[32768];  // 64KB: [half][buf][K 4KB | VT 4KB]
  int tid = threadIdx.x;
  int w = tid >> 6, l = tid & 63;
  int half = w >> 2, wl = w & 3;
  int hi = l >> 5, l31 = l & 31;
  int h = blockIdx.y, bx = blockIdx.x;
  int qrow = bx * 128 + wl * 32 + l31;
  bf16x8 qf[4];
#pragma unroll
  for (int ds = 0; ds < 4; ++ds)
    qf[ds] = *(const bf16x8*)(qp + (size_t)qrow * 1024 + h * 64 + ds * 16 + hi * 8);

  f32x16 zero16;
#pragma unroll
  for (int r = 0; r < 16; ++r) zero16[r] = 0.f;
  f32x16 accO[2];
#pragma unroll
  for (int r = 0; r < 16; ++r) { accO[0][r] = 0.f; accO[1][r] = 0.f; }
  float l_run = 0.f;

  u16* sbase = smem + half * 16384;
  int ht = (wl << 6) | l;  // half-local thread id, 0..255
  const u16* srcK[2]; const u16* srcV[2]; int dstOff[2];
#pragma unroll
  for (int i = 0; i < 2; ++i) {
    int id = i * 256 + ht;
    int r = id >> 3, cp = id & 7;
    int cl = cp ^ ((r ^ (r >> 3)) & 7);  // inverse swizzle on source (rule #21)
    srcK[i] = kp + (size_t)(half * 2048 + r) * 1024 + h * 64 + cl * 8;
    srcV[i] = vt + (size_t)(h * 64 + r) * 4096 + half * 2048 + cl * 8;
    dstOff[i] = id * 8;
  }
  auto stage = [&](int buf, int kt) {
    u16* b = sbase + buf * 8192;
#pragma unroll
    for (int i = 0; i < 2; ++i) {
      gl_lds16(srcK[i] + (size_t)kt * 65536, b + dstOff[i]);
      gl_lds16(srcV[i] + kt * 64, b + 4096 + dstOff[i]);
    }
  };
  stage(0, 0);
  __syncthreads();

  for (int kt = 0; kt < 32; ++kt) {
    int buf = kt & 1;
    if (kt < 31) stage(buf ^ 1, kt + 1);
    const u16* Kt = sbase + buf * 8192;
    const u16* Vt = Kt + 4096;

    // S^T = K @ Q^T (rows kv, cols q), log2 domain (Q pre-scaled)
    f32x16 accS[2];
    __builtin_amdgcn_s_setprio(1);
#pragma unroll
    for (int mt = 0; mt < 2; ++mt) {
      int row = mt * 32 + l31;
      int g = (row ^ (row >> 3)) & 7;
      {
        bf16x8 kf = *(const bf16x8*)(Kt + row * 64 + ((0 + hi) ^ g) * 8);
        accS[mt] = __builtin_amdgcn_mfma_f32_32x32x16_bf16(kf, qf[0], zero16, 0, 0, 0);
      }
#pragma unroll
      for (int ds = 1; ds < 4; ++ds) {
        int phys = (2 * ds + hi) ^ g;
        bf16x8 kf = *(const bf16x8*)(Kt + row * 64 + phys * 8);
        accS[mt] = __builtin_amdgcn_mfma_f32_32x32x16_bf16(kf, qf[ds], accS[mt], 0, 0, 0);
      }
    }
    __builtin_amdgcn_s_setprio(0);

    // p = exp2(s) directly; l partials on VALU; cross-lane shfl deferred
    u32 pku[2][8];
    float s0 = 0.f, s1 = 0.f, s2 = 0.f, s3 = 0.f;
#pragma unroll
    for (int mt = 0; mt < 2; ++mt)
#pragma unroll
      for (int qd = 0; qd < 8; ++qd) {
        float a = ex2(accS[mt][2 * qd]);
        float b = ex2(accS[mt][2 * qd + 1]);
        if (qd & 1) { s2 += a; s3 += b; } else { s0 += a; s1 += b; }
        pku[mt][qd] = pack2(a, b);
      }
    l_run += (s0 + s1) + (s2 + s3);

    // assemble P^T B-frags via permlane32_swap (A_hi <-> B_lo):
    bf16x8 pb[4];
#pragma unroll
    for (int ks = 0; ks < 4; ++ks) {
      const int mt = ks >> 1, k1 = ks & 1;
      u32 a0 = pku[mt][4 * k1 + 0], c0 = pku[mt][4 * k1 + 2];
      u32 a1 = pku[mt][4 * k1 + 1], c1 = pku[mt][4 * k1 + 3];
      asm("v_permlane32_swap_b32 %0, %1" : "+v"(a0), "+v"(c0));
      asm("v_permlane32_swap_b32 %0, %1" : "+v"(a1), "+v"(c1));
      u32x4 fr;
      fr[0] = a0; fr[1] = a1; fr[2] = c0; fr[3] = c1;
      pb[ks] = __builtin_bit_cast(bf16x8, fr);
    }
    // O^T += V^T @ P^T
    __builtin_amdgcn_s_setprio(1);
#pragma unroll
    for (int mto = 0; mto < 2; ++mto) {
      int row = mto * 32 + l31;
      int g = (row ^ (row >> 3)) & 7;
#pragma unroll
      for (int ks = 0; ks < 4; ++ks) {
        int phys = (2 * ks + hi) ^ g;
        bf16x8 vf = *(const bf16x8*)(Vt + row * 64 + phys * 8);
        accO[mto] = __builtin_amdgcn_mfma_f32_32x32x16_bf16(vf, pb[ks], accO[mto], 0, 0, 0);
      }
    }
    __builtin_amdgcn_s_setprio(0);
    __syncthreads();
  }
  l_run += __shfl_xor(l_run, 32, 64);   // deferred cross-lane l reduce

  // -------- cross-half combine: O = (O_A + O_B) / (l_A + l_B) --------
  u16* pO = smem;
  float* ml = (float*)(smem + 2 * 128 * 72);
  int q = wl * 32 + l31;
#pragma unroll
  for (int mto = 0; mto < 2; ++mto)
#pragma unroll
    for (int g = 0; g < 4; ++g)
#pragma unroll
      for (int j = 0; j < 2; ++j) {
        int r = g * 4 + j * 2;
        int d = j * 2 + 8 * g + 4 * hi + 32 * mto;
        u32 pk = pack2(accO[mto][r], accO[mto][r + 1]);
        *(u32*)&pO[(size_t)(half * 128 + q) * 72 + d] = pk;
      }
  if (hi == 0) ml[half * 128 + q] = l_run;
  __syncthreads();
  {
    int qq = tid >> 2, d0 = (tid & 3) * 16;   // 512 thr x 16 cols = 128x64
    float invL = 1.f / (ml[qq] + ml[128 + qq]);
    u16x8 ra0 = *(u16x8*)&pO[(size_t)qq * 72 + d0];
    u16x8 ra1 = *(u16x8*)&pO[(size_t)qq * 72 + d0 + 8];
    u16x8 rb0 = *(u16x8*)&pO[(size_t)(128 + qq) * 72 + d0];
    u16x8 rb1 = *(u16x8*)&pO[(size_t)(128 + qq) * 72 + d0 + 8];
    u16x8 o0, o1;
#pragma unroll
    for (int j = 0; j < 8; ++j) {
      o0[j] = f2bf((bf2f(ra0[j]) + bf2f(rb0[j])) * invL);
      o1[j] = f2bf((bf2f(ra1[j]) + bf2f(rb1[j])) * invL);
    }
    size_t ob = (size_t)(bx * 128 + qq) * 1024 + (size_t)h * 64 + d0;
    *(u16x8*)(attout + ob) = o0;
    *(u16x8*)(attout + ob + 8) = o1;
  }
}

// ---------------- 7. LayerNorm in-place on d_out ----------------------------
__global__ __launch_bounds__(256) void ln_kernel(float* __restrict__ io,
                                                 const float* __restrict__ gamma,
                                                 const float* __restrict__ beta) {
  int row = blockIdx.x, t = threadIdx.x;
  float4 v = *(const float4*)(io + (size_t)row * 1024 + t * 4);
  float s = v.x + v.y + v.z + v.w;
  float sq = v.x * v.x + v.y * v.y + v.z * v.z + v.w * v.w;
#pragma unroll
  for (int off = 1; off < 64; off <<= 1) {
    s += __shfl_xor(s, off, 64);
    sq += __shfl_xor(sq, off, 64);
  }
  __shared__ float rs[4], rq[4];
  if ((t & 63) == 0) { rs[t >> 6] = s; rq[t >> 6] = sq; }
  __syncthreads();
  float S = rs[0] + rs[1] + rs[2] + rs[3];
  float Q = rq[0] + rq[1] + rq[2] + rq[3];
  float mu = S * (1.f / 1024.f);
  float var = Q * (1.f / 1024.f) - mu * mu;
  float invs = rsqrtf(var + 1e-12f);
  float4 g = *(const float4*)(gamma + t * 4);
  float4 b = *(const float4*)(beta + t * 4);
  float4 o;
  o.x = (v.x - mu) * invs * g.x + b.x;
  o.y = (v.y - mu) * invs * g.y + b.y;
  o.z = (v.z - mu) * invs * g.z + b.z;
  o.w = (v.w - mu) * invs * g.w + b.w;
  *(float4*)(io + (size_t)row * 1024 + t * 4) = o;
}

extern "C" void kernel_launch(void* const* d_in, const int* in_sizes, int n_in,
                              void* d_out, int out_size, void* d_ws, size_t ws_size,
                              hipStream_t stream) {
  (void)in_sizes; (void)n_in; (void)out_size; (void)ws_size;
  const float* queries = (const float*)d_in[0];
  const float* keys    = (const float*)d_in[1];
  const float* values  = (const float*)d_in[2];
  const float* Wq = (const float*)d_in[3];
  const float* bq = (const float*)d_in[4];
  const float* Wk = (const float*)d_in[5];
  const float* bk = (const float*)d_in[6];
  const float* Wv = (const float*)d_in[7];
  const float* bv = (const float*)d_in[8];
  const float* Wo = (const float*)d_in[9];
  const float* bo = (const float*)d_in[10];
  const float* gamma = (const float*)d_in[11];
  const float* beta  = (const float*)d_in[12];
  float* out = (float*)d_out;

  u16* ws = (u16*)d_ws;
  u16* attout = ws;                 // 4096x1024
  u16* vt     = ws + 4194304;       // [16][64][4096]
  u16* wcatT  = ws + 12582912;      // 3x 1024x1024
  u16* woT    = ws + 15728640;      // 1024x1024
  u16* qp     = ws + 16777216;      // q,k,v projections contiguous
  u16* kp     = qp + 4194304;
  u16* vp     = qp + 8388608;

  prep_kernel<<<dim3(16, 16, 4), dim3(256), 0, stream>>>(Wq, Wk, Wv, Wo, wcatT, woT);
  gemm_bt<<<dim3(8, 96), dim3(512), 0, stream>>>(queries, keys, values, wcatT, qp,
                                                 bq, bk, bv);
  vtrans_kernel<<<dim3(64, 16), dim3(256), 0, stream>>>(vp, vt);
  attn_kernel<<<dim3(32, 16), dim3(512), 0, stream>>>(qp, kp, vt, attout);
  gemm_n64<<<dim3(8, 64), dim3(512), 0, stream>>>(attout, woT, out, bo, queries);
  ln_kernel<<<dim3(4096), dim3(256), 0, stream>>>(out, gamma, beta);
}